// Round 1
// baseline (31.034 us; speedup 1.0000x reference)
//
#include <hip/hip_runtime.h>
#include <hip/hip_bf16.h>

#define H 256
#define R_N 256
#define F_N 1024

// ---------------------------------------------------------------------------
// Kernel 1: compute
//   u[r,:] = (relu(rf @ r_w1 + r_b1) @ r_w2 + r_b2) @ w1_r           (256x256)
//   v[f,:] = (relu(ff @ f_w1 + f_b1) @ f_w2 + f_b2) @ w1_f + a_b1    (1024x256)
// Blocks 0..63: robot rows (4 per block). Blocks 64..319: frontier rows (4 per block).
// 256 threads = one output column each; 4-row register blocking so each
// weight-column load is reused 4x.
// ---------------------------------------------------------------------------
__global__ __launch_bounds__(256) void embed_kernel(
    const float* __restrict__ rf, const float* __restrict__ ff,
    const float* __restrict__ r_w1, const float* __restrict__ r_b1,
    const float* __restrict__ r_w2, const float* __restrict__ r_b2,
    const float* __restrict__ f_w1, const float* __restrict__ f_b1,
    const float* __restrict__ f_w2, const float* __restrict__ f_b2,
    const float* __restrict__ a_w1, const float* __restrict__ a_b1,
    float* __restrict__ u, float* __restrict__ v)
{
    const int t = threadIdx.x;
    __shared__ float a_s[4][H];   // layer-1 activations for the 4 rows
    __shared__ float e_s[4][H];   // embeddings for the 4 rows

    if (blockIdx.x < 64) {
        // ----- robot path -----
        const int r0 = blockIdx.x * 4;
        #pragma unroll
        for (int g = 0; g < 4; ++g) {
            const int r = r0 + g;
            float acc = r_b1[t];
            acc = fmaf(rf[r * 4 + 0], r_w1[0 * H + t], acc);
            acc = fmaf(rf[r * 4 + 1], r_w1[1 * H + t], acc);
            acc = fmaf(rf[r * 4 + 2], r_w1[2 * H + t], acc);
            acc = fmaf(rf[r * 4 + 3], r_w1[3 * H + t], acc);
            a_s[g][t] = fmaxf(acc, 0.0f);
        }
        __syncthreads();

        float e0 = r_b2[t], e1 = e0, e2 = e0, e3 = e0;
        #pragma unroll 8
        for (int k = 0; k < H; ++k) {
            const float w = r_w2[k * H + t];
            e0 = fmaf(a_s[0][k], w, e0);
            e1 = fmaf(a_s[1][k], w, e1);
            e2 = fmaf(a_s[2][k], w, e2);
            e3 = fmaf(a_s[3][k], w, e3);
        }
        __syncthreads();
        e_s[0][t] = e0; e_s[1][t] = e1; e_s[2][t] = e2; e_s[3][t] = e3;
        __syncthreads();

        float u0 = 0.f, u1 = 0.f, u2 = 0.f, u3 = 0.f;
        #pragma unroll 8
        for (int n = 0; n < H; ++n) {
            const float w = a_w1[n * H + t];   // w1_r rows 0..255
            u0 = fmaf(e_s[0][n], w, u0);
            u1 = fmaf(e_s[1][n], w, u1);
            u2 = fmaf(e_s[2][n], w, u2);
            u3 = fmaf(e_s[3][n], w, u3);
        }
        u[(r0 + 0) * H + t] = u0;
        u[(r0 + 1) * H + t] = u1;
        u[(r0 + 2) * H + t] = u2;
        u[(r0 + 3) * H + t] = u3;
    } else {
        // ----- frontier path -----
        const int f0 = (blockIdx.x - 64) * 4;
        #pragma unroll
        for (int g = 0; g < 4; ++g) {
            const int f = f0 + g;
            float acc = f_b1[t];
            acc = fmaf(ff[f * 3 + 0], f_w1[0 * H + t], acc);
            acc = fmaf(ff[f * 3 + 1], f_w1[1 * H + t], acc);
            acc = fmaf(ff[f * 3 + 2], f_w1[2 * H + t], acc);
            a_s[g][t] = fmaxf(acc, 0.0f);
        }
        __syncthreads();

        float e0 = f_b2[t], e1 = e0, e2 = e0, e3 = e0;
        #pragma unroll 8
        for (int k = 0; k < H; ++k) {
            const float w = f_w2[k * H + t];
            e0 = fmaf(a_s[0][k], w, e0);
            e1 = fmaf(a_s[1][k], w, e1);
            e2 = fmaf(a_s[2][k], w, e2);
            e3 = fmaf(a_s[3][k], w, e3);
        }
        __syncthreads();
        e_s[0][t] = e0; e_s[1][t] = e1; e_s[2][t] = e2; e_s[3][t] = e3;
        __syncthreads();

        const float bias = a_b1[t];
        float v0 = bias, v1 = bias, v2 = bias, v3 = bias;
        #pragma unroll 8
        for (int n = 0; n < H; ++n) {
            const float w = a_w1[(H + n) * H + t];   // w1_f rows 256..511
            v0 = fmaf(e_s[0][n], w, v0);
            v1 = fmaf(e_s[1][n], w, v1);
            v2 = fmaf(e_s[2][n], w, v2);
            v3 = fmaf(e_s[3][n], w, v3);
        }
        v[(f0 + 0) * H + t] = v0;
        v[(f0 + 1) * H + t] = v1;
        v[(f0 + 2) * H + t] = v2;
        v[(f0 + 3) * H + t] = v3;
    }
}

// ---------------------------------------------------------------------------
// Kernel 2: affinity[r,f] = sum_k relu(u[r,k] + v[f,k]) * w2[k] + b2
// 32x32 output tile per block, 256 threads, 2x2 outputs per thread.
// u/v tiles staged in LDS with pad stride 260 (float4-aligned, bank-friendly).
// ---------------------------------------------------------------------------
#define PAD 260

__global__ __launch_bounds__(256) void affinity_kernel(
    const float* __restrict__ u, const float* __restrict__ v,
    const float* __restrict__ a_w2, const float* __restrict__ a_b2,
    float* __restrict__ out)
{
    __shared__ float u_s[32][PAD];
    __shared__ float v_s[32][PAD];
    __shared__ float w_s[H];

    const int t  = threadIdx.x;
    const int r0 = (blockIdx.x >> 5) * 32;        // 8 r-tiles
    const int f0 = (blockIdx.x & 31) * 32;        // 32 f-tiles

    w_s[t] = a_w2[t];

    {
        const int rr = t >> 6;          // 0..3
        const int cc = (t & 63) << 2;   // 0,4,...,252
        #pragma unroll
        for (int i = 0; i < 8; ++i) {
            const int row = rr + i * 4;
            *(float4*)&u_s[row][cc] = *(const float4*)&u[(r0 + row) * H + cc];
            *(float4*)&v_s[row][cc] = *(const float4*)&v[(f0 + row) * H + cc];
        }
    }
    __syncthreads();

    const int fi = t & 15;
    const int ri = t >> 4;

    float acc00 = 0.f, acc01 = 0.f, acc10 = 0.f, acc11 = 0.f;
    #pragma unroll 4
    for (int k = 0; k < H; k += 4) {
        const float4 w4 = *(const float4*)&w_s[k];
        const float4 ua = *(const float4*)&u_s[ri][k];
        const float4 ub = *(const float4*)&u_s[ri + 16][k];
        const float4 va = *(const float4*)&v_s[fi][k];
        const float4 vb = *(const float4*)&v_s[fi + 16][k];

        acc00 = fmaf(fmaxf(ua.x + va.x, 0.f), w4.x, acc00);
        acc00 = fmaf(fmaxf(ua.y + va.y, 0.f), w4.y, acc00);
        acc00 = fmaf(fmaxf(ua.z + va.z, 0.f), w4.z, acc00);
        acc00 = fmaf(fmaxf(ua.w + va.w, 0.f), w4.w, acc00);

        acc01 = fmaf(fmaxf(ua.x + vb.x, 0.f), w4.x, acc01);
        acc01 = fmaf(fmaxf(ua.y + vb.y, 0.f), w4.y, acc01);
        acc01 = fmaf(fmaxf(ua.z + vb.z, 0.f), w4.z, acc01);
        acc01 = fmaf(fmaxf(ua.w + vb.w, 0.f), w4.w, acc01);

        acc10 = fmaf(fmaxf(ub.x + va.x, 0.f), w4.x, acc10);
        acc10 = fmaf(fmaxf(ub.y + va.y, 0.f), w4.y, acc10);
        acc10 = fmaf(fmaxf(ub.z + va.z, 0.f), w4.z, acc10);
        acc10 = fmaf(fmaxf(ub.w + va.w, 0.f), w4.w, acc10);

        acc11 = fmaf(fmaxf(ub.x + vb.x, 0.f), w4.x, acc11);
        acc11 = fmaf(fmaxf(ub.y + vb.y, 0.f), w4.y, acc11);
        acc11 = fmaf(fmaxf(ub.z + vb.z, 0.f), w4.z, acc11);
        acc11 = fmaf(fmaxf(ub.w + vb.w, 0.f), w4.w, acc11);
    }

    const float b = a_b2[0];
    out[(r0 + ri)      * F_N + f0 + fi]      = acc00 + b;
    out[(r0 + ri)      * F_N + f0 + fi + 16] = acc01 + b;
    out[(r0 + ri + 16) * F_N + f0 + fi]      = acc10 + b;
    out[(r0 + ri + 16) * F_N + f0 + fi + 16] = acc11 + b;
}

extern "C" void kernel_launch(void* const* d_in, const int* in_sizes, int n_in,
                              void* d_out, int out_size, void* d_ws, size_t ws_size,
                              hipStream_t stream) {
    const float* rf   = (const float*)d_in[0];
    const float* ff   = (const float*)d_in[1];
    const float* r_w1 = (const float*)d_in[2];
    const float* r_b1 = (const float*)d_in[3];
    const float* r_w2 = (const float*)d_in[4];
    const float* r_b2 = (const float*)d_in[5];
    const float* f_w1 = (const float*)d_in[6];
    const float* f_b1 = (const float*)d_in[7];
    const float* f_w2 = (const float*)d_in[8];
    const float* f_b2 = (const float*)d_in[9];
    const float* a_w1 = (const float*)d_in[10];
    const float* a_b1 = (const float*)d_in[11];
    const float* a_w2 = (const float*)d_in[12];
    const float* a_b2 = (const float*)d_in[13];

    float* u = (float*)d_ws;                 // 256*256 f32
    float* v = u + R_N * H;                  // 1024*256 f32

    embed_kernel<<<320, 256, 0, stream>>>(rf, ff, r_w1, r_b1, r_w2, r_b2,
                                          f_w1, f_b1, f_w2, f_b2,
                                          a_w1, a_b1, u, v);
    affinity_kernel<<<256, 256, 0, stream>>>(u, v, a_w2, a_b2, (float*)d_out);
}